// Round 5
// baseline (462.371 us; speedup 1.0000x reference)
//
#include <hip/hip_runtime.h>

constexpr int Bn  = 524288;
constexpr int Cn  = 42;
constexpr int BC  = Bn * Cn;     // 22020096
constexpr int BC4 = BC / 4;      // 5505024 (multiple of 42)
constexpr int B4  = Bn / 4;      // 131072
constexpr float EPSf = 1e-7f;

typedef float f4 __attribute__((ext_vector_type(4)));

__device__ __forceinline__ float frcp(float x) { return __builtin_amdgcn_rcpf(x); }

// ---------------- Kernel A: transmittances (pure stream) ----------------
// reads tau (704 MB) + mu (4 MB), writes t_direct/t_diffuse (176 MB).
__global__ __launch_bounds__(256) void trans_kernel(
    const float* __restrict__ tau,
    const float* __restrict__ mu_direct,
    const float* __restrict__ mu_diffuse,
    float* __restrict__ out)
{
    const int p = blockIdx.x * 256 + threadIdx.x;   // < BC4, exact grid
    const int b = p / Cn;
#pragma unroll
    for (int q = 0; q < 4; ++q) {
        const int pq = p + q * BC4;
        const f4* t4 = reinterpret_cast<const f4*>(tau) + pq * 2;
        f4 ta = t4[0], tb = t4[1];
        float tt = ((ta.x + ta.y) + (ta.z + ta.w)) + ((tb.x + tb.y) + (tb.z + tb.w));
        const int bq = b + q * B4;
        float md = mu_direct[bq];
        float mf = mu_diffuse[bq];
        out[pq]      = __expf(-tt * frcp(md + EPSf));
        out[BC + pq] = __expf(-tt * frcp(mf + EPSf));
    }
}

// ---------------- Kernel B: the two MLP heads + softmax ----------------
// LDS weight layout (R1-proven, conflict-free): 213 rows x 42 ch, stride 42.
// Rows 0..108   : direct net   (L1: o*10+i, bias o*10+9 | L2: 50+o*6+i,+5 | L3: 74+o*5+i,+4 | L4: 94+o*5+i,+4)
// Rows 109..212 : diffuse net  (L1: 109+o*9+i,+8 | L2: 154+o*6+i,+5 | L3: 178+o*5+i,+4 | L4: 198+o*5+i,+4)
__global__ __launch_bounds__(256) void mlp_kernel(
    const float* __restrict__ mu_direct,
    const float* __restrict__ cons,
    const float* __restrict__ dW1, const float* __restrict__ db1,
    const float* __restrict__ dW2, const float* __restrict__ db2,
    const float* __restrict__ dW3, const float* __restrict__ db3,
    const float* __restrict__ dW4, const float* __restrict__ db4,
    const float* __restrict__ fW1, const float* __restrict__ fb1,
    const float* __restrict__ fW2, const float* __restrict__ fb2,
    const float* __restrict__ fW3, const float* __restrict__ fb3,
    const float* __restrict__ fW4, const float* __restrict__ fb4,
    float* __restrict__ out)
{
    __shared__ float lds[213 * 42];

    auto stage = [&](const float* __restrict__ src, int n, int per_c, auto rowfn) {
        for (int i = threadIdx.x; i < n; i += 256) {
            int cc  = i / per_c;
            int rem = i - cc * per_c;
            lds[rowfn(rem) * 42 + cc] = src[i];
        }
    };
    // direct net
    stage(dW1, 1890, 45, [](int r) { return (r / 9) * 10 + (r % 9); });
    stage(db1,  210,  5, [](int r) { return r * 10 + 9; });
    stage(dW2,  840, 20, [](int r) { return 50 + (r / 5) * 6 + (r % 5); });
    stage(db2,  168,  4, [](int r) { return 50 + r * 6 + 5; });
    stage(dW3,  672, 16, [](int r) { return 74 + (r / 4) * 5 + (r % 4); });
    stage(db3,  168,  4, [](int r) { return 74 + r * 5 + 4; });
    stage(dW4,  504, 12, [](int r) { return 94 + (r / 4) * 5 + (r % 4); });
    stage(db4,  126,  3, [](int r) { return 94 + r * 5 + 4; });
    // diffuse net
    stage(fW1, 1680, 40, [](int r) { return 109 + (r / 8) * 9 + (r % 8); });
    stage(fb1,  210,  5, [](int r) { return 109 + r * 9 + 8; });
    stage(fW2,  840, 20, [](int r) { return 154 + (r / 5) * 6 + (r % 5); });
    stage(fb2,  168,  4, [](int r) { return 154 + r * 6 + 5; });
    stage(fW3,  672, 16, [](int r) { return 178 + (r / 4) * 5 + (r % 4); });
    stage(fb3,  168,  4, [](int r) { return 178 + r * 5 + 4; });
    stage(fW4,  504, 12, [](int r) { return 198 + (r / 4) * 5 + (r % 4); });
    stage(fb4,  126,  3, [](int r) { return 198 + r * 5 + 4; });
    __syncthreads();

    const int p = blockIdx.x * 256 + threadIdx.x;   // < BC4, exact grid
    const int c = p % Cn;
    const int b = p / Cn;
    const float* wc = lds + c;   // row r at wc[r*42]

    float mud[4], invd[4];
    float xc[4][8];

#pragma unroll
    for (int q = 0; q < 4; ++q) {
        const int bq = b + q * B4;
        float md = mu_direct[bq];
        const f4* c4 = reinterpret_cast<const f4*>(cons) + bq * 2;
        f4 ca = c4[0], cb = c4[1];
        xc[q][0] = ca.x; xc[q][1] = ca.y; xc[q][2] = ca.z; xc[q][3] = ca.w;
        xc[q][4] = cb.x; xc[q][5] = cb.y; xc[q][6] = cb.z; xc[q][7] = cb.w;
        mud[q] = md; invd[q] = frcp(md + EPSf);
    }

    float h1[4][5], h2[4][4], h3[4][4], oo[4][3];

    // ---------------- diffuse net (input: raw constituents) ----------------
#pragma unroll
    for (int o = 0; o < 5; ++o) {
        float a0 = 0.f, a1 = 0.f, a2 = 0.f, a3 = 0.f;
#pragma unroll
        for (int i = 0; i < 8; ++i) {
            float w = wc[(109 + o * 9 + i) * 42];
            a0 = fmaf(w, xc[0][i], a0);
            a1 = fmaf(w, xc[1][i], a1);
            a2 = fmaf(w, xc[2][i], a2);
            a3 = fmaf(w, xc[3][i], a3);
        }
        float bs = wc[(109 + o * 9 + 8) * 42];
        h1[0][o] = fmaxf(a0 + bs, 0.f);
        h1[1][o] = fmaxf(a1 + bs, 0.f);
        h1[2][o] = fmaxf(a2 + bs, 0.f);
        h1[3][o] = fmaxf(a3 + bs, 0.f);
    }
#pragma unroll
    for (int o = 0; o < 4; ++o) {
        float a0 = 0.f, a1 = 0.f, a2 = 0.f, a3 = 0.f;
#pragma unroll
        for (int i = 0; i < 5; ++i) {
            float w = wc[(154 + o * 6 + i) * 42];
            a0 = fmaf(w, h1[0][i], a0);
            a1 = fmaf(w, h1[1][i], a1);
            a2 = fmaf(w, h1[2][i], a2);
            a3 = fmaf(w, h1[3][i], a3);
        }
        float bs = wc[(154 + o * 6 + 5) * 42];
        h2[0][o] = fmaxf(a0 + bs, 0.f);
        h2[1][o] = fmaxf(a1 + bs, 0.f);
        h2[2][o] = fmaxf(a2 + bs, 0.f);
        h2[3][o] = fmaxf(a3 + bs, 0.f);
    }
#pragma unroll
    for (int o = 0; o < 4; ++o) {
        float a0 = 0.f, a1 = 0.f, a2 = 0.f, a3 = 0.f;
#pragma unroll
        for (int i = 0; i < 4; ++i) {
            float w = wc[(178 + o * 5 + i) * 42];
            a0 = fmaf(w, h2[0][i], a0);
            a1 = fmaf(w, h2[1][i], a1);
            a2 = fmaf(w, h2[2][i], a2);
            a3 = fmaf(w, h2[3][i], a3);
        }
        float bs = wc[(178 + o * 5 + 4) * 42];
        h3[0][o] = fmaxf(a0 + bs, 0.f);
        h3[1][o] = fmaxf(a1 + bs, 0.f);
        h3[2][o] = fmaxf(a2 + bs, 0.f);
        h3[3][o] = fmaxf(a3 + bs, 0.f);
    }
#pragma unroll
    for (int o = 0; o < 3; ++o) {
        float a0 = 0.f, a1 = 0.f, a2 = 0.f, a3 = 0.f;
#pragma unroll
        for (int i = 0; i < 4; ++i) {
            float w = wc[(198 + o * 5 + i) * 42];
            a0 = fmaf(w, h3[0][i], a0);
            a1 = fmaf(w, h3[1][i], a1);
            a2 = fmaf(w, h3[2][i], a2);
            a3 = fmaf(w, h3[3][i], a3);
        }
        float bs = wc[(198 + o * 5 + 4) * 42];
        oo[0][o] = a0 + bs; oo[1][o] = a1 + bs; oo[2][o] = a2 + bs; oo[3][o] = a3 + bs;
    }
#pragma unroll
    for (int q = 0; q < 4; ++q) {
        float v0 = oo[q][0], v1 = oo[q][1], v2 = oo[q][2];
        float m = fmaxf(fmaxf(v0, v1), v2);
        float e0 = __expf(v0 - m), e1 = __expf(v1 - m), e2 = __expf(v2 - m);
        float rs = frcp(e0 + e1 + e2);
        int base = 5 * BC + (p + q * BC4) * 3;
        out[base + 0] = e0 * rs;
        out[base + 1] = e1 * rs;
        out[base + 2] = e2 * rs;
    }

    // ---------------- direct net (input: [cons/(mu_d+eps), mu_d]) ----------------
#pragma unroll
    for (int q = 0; q < 4; ++q)
#pragma unroll
        for (int i = 0; i < 8; ++i) xc[q][i] *= invd[q];

#pragma unroll
    for (int o = 0; o < 5; ++o) {
        float a0 = 0.f, a1 = 0.f, a2 = 0.f, a3 = 0.f;
#pragma unroll
        for (int i = 0; i < 9; ++i) {
            float w = wc[(o * 10 + i) * 42];
            float x0 = (i < 8) ? xc[0][i] : mud[0];
            float x1 = (i < 8) ? xc[1][i] : mud[1];
            float x2 = (i < 8) ? xc[2][i] : mud[2];
            float x3 = (i < 8) ? xc[3][i] : mud[3];
            a0 = fmaf(w, x0, a0);
            a1 = fmaf(w, x1, a1);
            a2 = fmaf(w, x2, a2);
            a3 = fmaf(w, x3, a3);
        }
        float bs = wc[(o * 10 + 9) * 42];
        h1[0][o] = fmaxf(a0 + bs, 0.f);
        h1[1][o] = fmaxf(a1 + bs, 0.f);
        h1[2][o] = fmaxf(a2 + bs, 0.f);
        h1[3][o] = fmaxf(a3 + bs, 0.f);
    }
#pragma unroll
    for (int o = 0; o < 4; ++o) {
        float a0 = 0.f, a1 = 0.f, a2 = 0.f, a3 = 0.f;
#pragma unroll
        for (int i = 0; i < 5; ++i) {
            float w = wc[(50 + o * 6 + i) * 42];
            a0 = fmaf(w, h1[0][i], a0);
            a1 = fmaf(w, h1[1][i], a1);
            a2 = fmaf(w, h1[2][i], a2);
            a3 = fmaf(w, h1[3][i], a3);
        }
        float bs = wc[(50 + o * 6 + 5) * 42];
        h2[0][o] = fmaxf(a0 + bs, 0.f);
        h2[1][o] = fmaxf(a1 + bs, 0.f);
        h2[2][o] = fmaxf(a2 + bs, 0.f);
        h2[3][o] = fmaxf(a3 + bs, 0.f);
    }
#pragma unroll
    for (int o = 0; o < 4; ++o) {
        float a0 = 0.f, a1 = 0.f, a2 = 0.f, a3 = 0.f;
#pragma unroll
        for (int i = 0; i < 4; ++i) {
            float w = wc[(74 + o * 5 + i) * 42];
            a0 = fmaf(w, h2[0][i], a0);
            a1 = fmaf(w, h2[1][i], a1);
            a2 = fmaf(w, h2[2][i], a2);
            a3 = fmaf(w, h2[3][i], a3);
        }
        float bs = wc[(74 + o * 5 + 4) * 42];
        h3[0][o] = fmaxf(a0 + bs, 0.f);
        h3[1][o] = fmaxf(a1 + bs, 0.f);
        h3[2][o] = fmaxf(a2 + bs, 0.f);
        h3[3][o] = fmaxf(a3 + bs, 0.f);
    }
#pragma unroll
    for (int o = 0; o < 3; ++o) {
        float a0 = 0.f, a1 = 0.f, a2 = 0.f, a3 = 0.f;
#pragma unroll
        for (int i = 0; i < 4; ++i) {
            float w = wc[(94 + o * 5 + i) * 42];
            a0 = fmaf(w, h3[0][i], a0);
            a1 = fmaf(w, h3[1][i], a1);
            a2 = fmaf(w, h3[2][i], a2);
            a3 = fmaf(w, h3[3][i], a3);
        }
        float bs = wc[(94 + o * 5 + 4) * 42];
        oo[0][o] = a0 + bs; oo[1][o] = a1 + bs; oo[2][o] = a2 + bs; oo[3][o] = a3 + bs;
    }
#pragma unroll
    for (int q = 0; q < 4; ++q) {
        float v0 = oo[q][0], v1 = oo[q][1], v2 = oo[q][2];
        float m = fmaxf(fmaxf(v0, v1), v2);
        float e0 = __expf(v0 - m), e1 = __expf(v1 - m), e2 = __expf(v2 - m);
        float rs = frcp(e0 + e1 + e2);
        int base = 2 * BC + (p + q * BC4) * 3;
        out[base + 0] = e0 * rs;
        out[base + 1] = e1 * rs;
        out[base + 2] = e2 * rs;
    }
}

extern "C" void kernel_launch(void* const* d_in, const int* in_sizes, int n_in,
                              void* d_out, int out_size, void* d_ws, size_t ws_size,
                              hipStream_t stream) {
    const float* tau  = (const float*)d_in[0];
    const float* mu_d = (const float*)d_in[1];
    const float* mu_f = (const float*)d_in[2];
    const float* cons = (const float*)d_in[3];

    dim3 grid(BC4 / 256);   // 21504 blocks each, exact cover of BC/4 threads

    trans_kernel<<<grid, 256, 0, stream>>>(tau, mu_d, mu_f, (float*)d_out);

    mlp_kernel<<<grid, 256, 0, stream>>>(
        mu_d, cons,
        (const float*)d_in[4],  (const float*)d_in[5],
        (const float*)d_in[6],  (const float*)d_in[7],
        (const float*)d_in[8],  (const float*)d_in[9],
        (const float*)d_in[10], (const float*)d_in[11],
        (const float*)d_in[12], (const float*)d_in[13],
        (const float*)d_in[14], (const float*)d_in[15],
        (const float*)d_in[16], (const float*)d_in[17],
        (const float*)d_in[18], (const float*)d_in[19],
        (float*)d_out);
}

// Round 6
// 350.393 us; speedup vs baseline: 1.3196x; 1.3196x over previous
//
#include <hip/hip_runtime.h>

constexpr int Bn  = 524288;
constexpr int Cn  = 42;
constexpr int BC  = Bn * Cn;     // 22020096
constexpr int BC4 = BC / 4;      // 5505024 threads, each does 4 outputs
constexpr int QS  = 672;         // q-stride = 16*42: c preserved, b += 16
constexpr int TS  = 4 * QS;      // tile span = 2688 p's; BC / TS = 8192 tiles exactly
constexpr float EPSf = 1e-7f;

typedef float f4 __attribute__((ext_vector_type(4)));

__device__ __forceinline__ float frcp(float x) { return __builtin_amdgcn_rcpf(x); }

// LDS weight layout (R1-proven, conflict-free): 213 rows x 42 ch, stride 42.
// Rows 0..108   : direct net   (L1: o*10+i, bias o*10+9 | L2: 50+o*6+i,+5 | L3: 74+o*5+i,+4 | L4: 94+o*5+i,+4)
// Rows 109..212 : diffuse net  (L1: 109+o*9+i,+8 | L2: 154+o*6+i,+5 | L3: 178+o*5+i,+4 | L4: 198+o*5+i,+4)

__global__ __launch_bounds__(256) void scat_main(
    const float* __restrict__ tau,
    const float* __restrict__ mu_direct,
    const float* __restrict__ mu_diffuse,
    const float* __restrict__ cons,
    const float* __restrict__ dW1, const float* __restrict__ db1,
    const float* __restrict__ dW2, const float* __restrict__ db2,
    const float* __restrict__ dW3, const float* __restrict__ db3,
    const float* __restrict__ dW4, const float* __restrict__ db4,
    const float* __restrict__ fW1, const float* __restrict__ fb1,
    const float* __restrict__ fW2, const float* __restrict__ fb2,
    const float* __restrict__ fW3, const float* __restrict__ fb3,
    const float* __restrict__ fW4, const float* __restrict__ fb4,
    float* __restrict__ out)
{
    __shared__ float lds[213 * 42];

    auto stage = [&](const float* __restrict__ src, int n, int per_c, auto rowfn) {
        for (int i = threadIdx.x; i < n; i += 256) {
            int cc  = i / per_c;
            int rem = i - cc * per_c;
            lds[rowfn(rem) * 42 + cc] = src[i];
        }
    };
    // direct net
    stage(dW1, 1890, 45, [](int r) { return (r / 9) * 10 + (r % 9); });
    stage(db1,  210,  5, [](int r) { return r * 10 + 9; });
    stage(dW2,  840, 20, [](int r) { return 50 + (r / 5) * 6 + (r % 5); });
    stage(db2,  168,  4, [](int r) { return 50 + r * 6 + 5; });
    stage(dW3,  672, 16, [](int r) { return 74 + (r / 4) * 5 + (r % 4); });
    stage(db3,  168,  4, [](int r) { return 74 + r * 5 + 4; });
    stage(dW4,  504, 12, [](int r) { return 94 + (r / 4) * 5 + (r % 4); });
    stage(db4,  126,  3, [](int r) { return 94 + r * 5 + 4; });
    // diffuse net
    stage(fW1, 1680, 40, [](int r) { return 109 + (r / 8) * 9 + (r % 8); });
    stage(fb1,  210,  5, [](int r) { return 109 + r * 9 + 8; });
    stage(fW2,  840, 20, [](int r) { return 154 + (r / 5) * 6 + (r % 5); });
    stage(fb2,  168,  4, [](int r) { return 154 + r * 6 + 5; });
    stage(fW3,  672, 16, [](int r) { return 178 + (r / 4) * 5 + (r % 4); });
    stage(fb3,  168,  4, [](int r) { return 178 + r * 5 + 4; });
    stage(fW4,  504, 12, [](int r) { return 198 + (r / 4) * 5 + (r % 4); });
    stage(fb4,  126,  3, [](int r) { return 198 + r * 5 + 4; });
    __syncthreads();

    // tile-compact mapping: u -> tile of 2688 p's; thread owns p0 + q*672.
    const int u    = blockIdx.x * 256 + threadIdx.x;   // < BC4
    const int tile = u / QS;
    const int lane = u - tile * QS;
    const int p0   = tile * TS + lane;
    const int c    = lane % Cn;          // TS, QS are multiples of 42
    const int b0   = p0 / Cn;            // b for q: b0 + 16*q
    const float* wc = lds + c;           // row r at wc[r*42]

    float mud[4], invd[4];
    float xc[4][8];

    // tau reduction + transmittances + input loads
#pragma unroll
    for (int q = 0; q < 4; ++q) {
        const int pq = p0 + q * QS;
        const f4* t4 = reinterpret_cast<const f4*>(tau) + pq * 2;
        f4 ta = t4[0], tb = t4[1];
        float tt = ((ta.x + ta.y) + (ta.z + ta.w)) + ((tb.x + tb.y) + (tb.z + tb.w));
        const int bq = b0 + q * 16;
        float md = mu_direct[bq];
        float mf = mu_diffuse[bq];
        const f4* c4 = reinterpret_cast<const f4*>(cons) + bq * 2;
        f4 ca = c4[0], cb = c4[1];
        xc[q][0] = ca.x; xc[q][1] = ca.y; xc[q][2] = ca.z; xc[q][3] = ca.w;
        xc[q][4] = cb.x; xc[q][5] = cb.y; xc[q][6] = cb.z; xc[q][7] = cb.w;
        float id = frcp(md + EPSf);
        float iff = frcp(mf + EPSf);
        out[pq]      = __expf(-tt * id);
        out[BC + pq] = __expf(-tt * iff);
        mud[q] = md; invd[q] = id;
    }

    float h1[4][5], h2[4][4], h3[4][4], oo[4][3];

    // ---------------- diffuse net (input: raw constituents) ----------------
#pragma unroll
    for (int o = 0; o < 5; ++o) {
        float a0 = 0.f, a1 = 0.f, a2 = 0.f, a3 = 0.f;
#pragma unroll
        for (int i = 0; i < 8; ++i) {
            float w = wc[(109 + o * 9 + i) * 42];
            a0 = fmaf(w, xc[0][i], a0);
            a1 = fmaf(w, xc[1][i], a1);
            a2 = fmaf(w, xc[2][i], a2);
            a3 = fmaf(w, xc[3][i], a3);
        }
        float bs = wc[(109 + o * 9 + 8) * 42];
        h1[0][o] = fmaxf(a0 + bs, 0.f);
        h1[1][o] = fmaxf(a1 + bs, 0.f);
        h1[2][o] = fmaxf(a2 + bs, 0.f);
        h1[3][o] = fmaxf(a3 + bs, 0.f);
    }
#pragma unroll
    for (int o = 0; o < 4; ++o) {
        float a0 = 0.f, a1 = 0.f, a2 = 0.f, a3 = 0.f;
#pragma unroll
        for (int i = 0; i < 5; ++i) {
            float w = wc[(154 + o * 6 + i) * 42];
            a0 = fmaf(w, h1[0][i], a0);
            a1 = fmaf(w, h1[1][i], a1);
            a2 = fmaf(w, h1[2][i], a2);
            a3 = fmaf(w, h1[3][i], a3);
        }
        float bs = wc[(154 + o * 6 + 5) * 42];
        h2[0][o] = fmaxf(a0 + bs, 0.f);
        h2[1][o] = fmaxf(a1 + bs, 0.f);
        h2[2][o] = fmaxf(a2 + bs, 0.f);
        h2[3][o] = fmaxf(a3 + bs, 0.f);
    }
#pragma unroll
    for (int o = 0; o < 4; ++o) {
        float a0 = 0.f, a1 = 0.f, a2 = 0.f, a3 = 0.f;
#pragma unroll
        for (int i = 0; i < 4; ++i) {
            float w = wc[(178 + o * 5 + i) * 42];
            a0 = fmaf(w, h2[0][i], a0);
            a1 = fmaf(w, h2[1][i], a1);
            a2 = fmaf(w, h2[2][i], a2);
            a3 = fmaf(w, h2[3][i], a3);
        }
        float bs = wc[(178 + o * 5 + 4) * 42];
        h3[0][o] = fmaxf(a0 + bs, 0.f);
        h3[1][o] = fmaxf(a1 + bs, 0.f);
        h3[2][o] = fmaxf(a2 + bs, 0.f);
        h3[3][o] = fmaxf(a3 + bs, 0.f);
    }
#pragma unroll
    for (int o = 0; o < 3; ++o) {
        float a0 = 0.f, a1 = 0.f, a2 = 0.f, a3 = 0.f;
#pragma unroll
        for (int i = 0; i < 4; ++i) {
            float w = wc[(198 + o * 5 + i) * 42];
            a0 = fmaf(w, h3[0][i], a0);
            a1 = fmaf(w, h3[1][i], a1);
            a2 = fmaf(w, h3[2][i], a2);
            a3 = fmaf(w, h3[3][i], a3);
        }
        float bs = wc[(198 + o * 5 + 4) * 42];
        oo[0][o] = a0 + bs; oo[1][o] = a1 + bs; oo[2][o] = a2 + bs; oo[3][o] = a3 + bs;
    }
#pragma unroll
    for (int q = 0; q < 4; ++q) {
        float v0 = oo[q][0], v1 = oo[q][1], v2 = oo[q][2];
        float m = fmaxf(fmaxf(v0, v1), v2);
        float e0 = __expf(v0 - m), e1 = __expf(v1 - m), e2 = __expf(v2 - m);
        float rs = frcp(e0 + e1 + e2);
        int base = 5 * BC + (p0 + q * QS) * 3;
        out[base + 0] = e0 * rs;
        out[base + 1] = e1 * rs;
        out[base + 2] = e2 * rs;
    }

    // ---------------- direct net (input: [cons/(mu_d+eps), mu_d]) ----------------
#pragma unroll
    for (int q = 0; q < 4; ++q)
#pragma unroll
        for (int i = 0; i < 8; ++i) xc[q][i] *= invd[q];

#pragma unroll
    for (int o = 0; o < 5; ++o) {
        float a0 = 0.f, a1 = 0.f, a2 = 0.f, a3 = 0.f;
#pragma unroll
        for (int i = 0; i < 9; ++i) {
            float w = wc[(o * 10 + i) * 42];
            float x0 = (i < 8) ? xc[0][i] : mud[0];
            float x1 = (i < 8) ? xc[1][i] : mud[1];
            float x2 = (i < 8) ? xc[2][i] : mud[2];
            float x3 = (i < 8) ? xc[3][i] : mud[3];
            a0 = fmaf(w, x0, a0);
            a1 = fmaf(w, x1, a1);
            a2 = fmaf(w, x2, a2);
            a3 = fmaf(w, x3, a3);
        }
        float bs = wc[(o * 10 + 9) * 42];
        h1[0][o] = fmaxf(a0 + bs, 0.f);
        h1[1][o] = fmaxf(a1 + bs, 0.f);
        h1[2][o] = fmaxf(a2 + bs, 0.f);
        h1[3][o] = fmaxf(a3 + bs, 0.f);
    }
#pragma unroll
    for (int o = 0; o < 4; ++o) {
        float a0 = 0.f, a1 = 0.f, a2 = 0.f, a3 = 0.f;
#pragma unroll
        for (int i = 0; i < 5; ++i) {
            float w = wc[(50 + o * 6 + i) * 42];
            a0 = fmaf(w, h1[0][i], a0);
            a1 = fmaf(w, h1[1][i], a1);
            a2 = fmaf(w, h1[2][i], a2);
            a3 = fmaf(w, h1[3][i], a3);
        }
        float bs = wc[(50 + o * 6 + 5) * 42];
        h2[0][o] = fmaxf(a0 + bs, 0.f);
        h2[1][o] = fmaxf(a1 + bs, 0.f);
        h2[2][o] = fmaxf(a2 + bs, 0.f);
        h2[3][o] = fmaxf(a3 + bs, 0.f);
    }
#pragma unroll
    for (int o = 0; o < 4; ++o) {
        float a0 = 0.f, a1 = 0.f, a2 = 0.f, a3 = 0.f;
#pragma unroll
        for (int i = 0; i < 4; ++i) {
            float w = wc[(74 + o * 5 + i) * 42];
            a0 = fmaf(w, h2[0][i], a0);
            a1 = fmaf(w, h2[1][i], a1);
            a2 = fmaf(w, h2[2][i], a2);
            a3 = fmaf(w, h2[3][i], a3);
        }
        float bs = wc[(74 + o * 5 + 4) * 42];
        h3[0][o] = fmaxf(a0 + bs, 0.f);
        h3[1][o] = fmaxf(a1 + bs, 0.f);
        h3[2][o] = fmaxf(a2 + bs, 0.f);
        h3[3][o] = fmaxf(a3 + bs, 0.f);
    }
#pragma unroll
    for (int o = 0; o < 3; ++o) {
        float a0 = 0.f, a1 = 0.f, a2 = 0.f, a3 = 0.f;
#pragma unroll
        for (int i = 0; i < 4; ++i) {
            float w = wc[(94 + o * 5 + i) * 42];
            a0 = fmaf(w, h3[0][i], a0);
            a1 = fmaf(w, h3[1][i], a1);
            a2 = fmaf(w, h3[2][i], a2);
            a3 = fmaf(w, h3[3][i], a3);
        }
        float bs = wc[(94 + o * 5 + 4) * 42];
        oo[0][o] = a0 + bs; oo[1][o] = a1 + bs; oo[2][o] = a2 + bs; oo[3][o] = a3 + bs;
    }
#pragma unroll
    for (int q = 0; q < 4; ++q) {
        float v0 = oo[q][0], v1 = oo[q][1], v2 = oo[q][2];
        float m = fmaxf(fmaxf(v0, v1), v2);
        float e0 = __expf(v0 - m), e1 = __expf(v1 - m), e2 = __expf(v2 - m);
        float rs = frcp(e0 + e1 + e2);
        int base = 2 * BC + (p0 + q * QS) * 3;
        out[base + 0] = e0 * rs;
        out[base + 1] = e1 * rs;
        out[base + 2] = e2 * rs;
    }
}

extern "C" void kernel_launch(void* const* d_in, const int* in_sizes, int n_in,
                              void* d_out, int out_size, void* d_ws, size_t ws_size,
                              hipStream_t stream) {
    const float* tau  = (const float*)d_in[0];
    const float* mu_d = (const float*)d_in[1];
    const float* mu_f = (const float*)d_in[2];
    const float* cons = (const float*)d_in[3];

    dim3 grid(BC4 / 256);   // 21504 blocks, exact cover
    scat_main<<<grid, 256, 0, stream>>>(
        tau, mu_d, mu_f, cons,
        (const float*)d_in[4],  (const float*)d_in[5],
        (const float*)d_in[6],  (const float*)d_in[7],
        (const float*)d_in[8],  (const float*)d_in[9],
        (const float*)d_in[10], (const float*)d_in[11],
        (const float*)d_in[12], (const float*)d_in[13],
        (const float*)d_in[14], (const float*)d_in[15],
        (const float*)d_in[16], (const float*)d_in[17],
        (const float*)d_in[18], (const float*)d_in[19],
        (float*)d_out);
}